// Round 1
// 143.940 us; speedup vs baseline: 1.0010x; 1.0010x over previous
//
#include <hip/hip_runtime.h>

// Detection post-process: softmax -> decode -> per-class LAZY NMS -> top-100.
// N=8 images, A=16384 anchors, C=21 classes (class 0 = background).
//
// R6 (144.2us): 512-chunk sort + LDS swizzle + ballot compaction + prefetched walk;
// topk = bitonic-2048.
// R7: counters show nms 61.5us latency-bound (Occ 12%, VALU 20%, HBM 1.8%) -- the
// barrier-chained bitonic stages are the pole (45 stages in nms, 66 in topk, each a
// full-block __syncthreads + dependent u64 LDS round-trip). Rewrite both sorts as
// hybrid shuffle/LDS bitonic: partner i^j is in-wave for j<=32 (u64 __shfl_xor, no
// barrier, no LDS); only j>=64 (nms) / j>=128 (topk) stages touch LDS.
// nms: 45 -> 6 LDS stages; topk: 66 -> 10 LDS stages (+ register key build, no fill).
// Identical compare-exchange network => bit-identical results.
// Exactness invariants (absmax 0.0 since R1):
//   - u64 key = (score_bits<<32)|~idx  => exact (score desc, idx asc) total order
//   - monotone bin(float bits) => bin-threshold selection is a key-order cut
//   - lazy NMS: dead entries never kill => test pops against accepted set only
//   - division-free EXACT IoU predicate:
//     RN_f32(inter/un) > 0.45f  <=>  (double)inter > ((double)0.45f + 2^-26)*(double)un

typedef unsigned long long u64;

#define N_IMG 8
#define A     16384
#define NCLS  21
#define NC    20
#define TOPK  100
#define PROB_THR 0.05f

#define TN     512         // nms threads (8 waves)
#define NSLOT  32          // scores per thread
#define NBIN   1152        // score-bit bins: (bits>>15)-31385 spans (0.05,1]
#define BINOFF 31385
#define CAPC   512         // chunk capacity (sorted); expected pops ~150-250
#define TARGET 384

#define PHYS(i) ((i) + ((i) >> 4))   // LDS u64 swizzle: breaks power-of-2 strides

#define MIDTHR ((double)0.45f + 0x1p-26)

__device__ __forceinline__ u64 pk(float v, int i) {
    return (v > 0.f) ? (((u64)__float_as_uint(v) << 32) | (u64)(unsigned)(~(unsigned)i)) : 0ull;
}
__device__ __forceinline__ float upv(u64 k) { return __uint_as_float((unsigned)(k >> 32)); }
__device__ __forceinline__ int   upi(u64 k) { return (int)(~(unsigned)k); }
__device__ __forceinline__ u64 umx(u64 a, u64 b) { return a > b ? a : b; }
__device__ __forceinline__ u64 umn(u64 a, u64 b) { return a < b ? a : b; }

// bitonic compare-exchange keep-rule for element i at stage (k,j):
// region (i&k)==0 sorts descending; lower partner ((i&j)==0) keeps max there.
__device__ __forceinline__ u64 bsel(u64 mine, u64 other, int i, int k, int j) {
    bool keep_max = ((i & k) == 0) == ((i & j) == 0);
    return keep_max ? umx(mine, other) : umn(mine, other);
}

__device__ __forceinline__ int binOf(float s) {
    int b = (int)(__float_as_uint(s) >> 15) - BINOFF;
    return b < 0 ? 0 : (b > NBIN - 1 ? NBIN - 1 : b);
}

// exact ref predicate: RN(inter/union) > 0.45f
__device__ __forceinline__ bool killp(float4 b, float ab, float4 s, float as_) {
    float lx = fmaxf(s.x, b.x), ly = fmaxf(s.y, b.y);
    float rx = fminf(s.z, b.z), ry = fminf(s.w, b.w);
    float iw = fmaxf(rx - lx, 0.f), ih = fmaxf(ry - ly, 0.f);
    float inter = iw * ih;
    float un = as_ + ab - inter;
    return (double)inter > MIDTHR * (double)un;
}

// Kernel 1: softmax + threshold -> scores[N][NC][A]; SSD decode -> clamped corner boxes.
__global__ __launch_bounds__(256) void preprocess_kernel(
    const float* __restrict__ cls, const float* __restrict__ reg,
    const float* __restrict__ anc, float4* __restrict__ boxes,
    float* __restrict__ scores) {
    __shared__ __align__(16) float lcls[256 * NCLS];
    const int tid = threadIdx.x;
    const int t = blockIdx.x * 256 + tid;

    const float4* src = (const float4*)(cls + (size_t)blockIdx.x * (256 * NCLS));
    float4* dst = (float4*)lcls;
    for (int i = tid; i < (256 * NCLS) / 4; i += 256) dst[i] = src[i];
    __syncthreads();

    const int n = t >> 14;
    const int a = t & (A - 1);
    const float* c = lcls + tid * NCLS;
    float z[NCLS];
    float m = -1e30f;
#pragma unroll
    for (int k = 0; k < NCLS; ++k) { z[k] = c[k]; m = fmaxf(m, z[k]); }
    float s = 0.f;
#pragma unroll
    for (int k = 0; k < NCLS; ++k) { z[k] = expf(z[k] - m); s += z[k]; }
    const float inv = 1.f / s;
#pragma unroll
    for (int k = 0; k < NC; ++k) {
        float p = z[k + 1] * inv;
        scores[(((size_t)n * NC + k) << 14) + a] = (p > PROB_THR) ? p : -1.f;
    }

    const float4 l4 = ((const float4*)reg)[t];
    const float4 an = ((const float4*)anc)[a];
    const float cx = an.x + l4.x * 0.1f * an.z;
    const float cy = an.y + l4.y * 0.1f * an.w;
    const float w  = an.z * expf(l4.z * 0.2f);
    const float h  = an.w * expf(l4.w * 0.2f);
    float x0 = fminf(fmaxf(cx - 0.5f * w, 0.f), 1.f);
    float y0 = fminf(fmaxf(cy - 0.5f * h, 0.f), 1.f);
    float x1 = fminf(fmaxf(cx + 0.5f * w, 0.f), 1.f);
    float y1 = fminf(fmaxf(cy + 0.5f * h, 0.f), 1.f);
    boxes[t] = make_float4(x0, y0, x1, y1);
}

// Kernel 2: one workgroup per (n, ci). Histogram-select -> sort-512 -> lazy walk.
__global__ __launch_bounds__(TN) void nms_kernel(
    const float4* __restrict__ boxes, const float* __restrict__ scores,
    float* __restrict__ rows) {
    __shared__ int bins[NBIN];
    __shared__ u64 skey[PHYS(CAPC - 1) + 2];
    __shared__ __align__(16) float4 sbox[CAPC];
    __shared__ u64 red8[TN / 64];
    __shared__ u64 bkey;
    __shared__ __align__(16) float4 bbox;
    __shared__ int sint[3];   // 0:B  1:cnt  2:degenerate

    const int blk = blockIdx.x, n = blk / NC, ci = blk % NC;
    const int tid = threadIdx.x, lane = tid & 63, w = tid >> 6;
    const float* gs = scores + ((size_t)blk << 14);
    const float4* gb = boxes + ((size_t)n << 14);
    float* grows = rows + (size_t)blk * 600;

    // scores -> registers (coalesced float4)
    float sc[NSLOT];
    const float4* gs4 = (const float4*)gs;
#pragma unroll
    for (int k = 0; k < NSLOT / 4; ++k) {
        float4 v = gs4[tid + (k << 9)];
        sc[k * 4 + 0] = v.x; sc[k * 4 + 1] = v.y; sc[k * 4 + 2] = v.z; sc[k * 4 + 3] = v.w;
    }
#define AIDX(t_) ((tid << 2) + (((t_) >> 2) << 11) + ((t_) & 3))

    float4 accA, accB;
    float arA = 0.f, arB = 0.f;
    int na = 0;
    u64 filter = ~0ull;
    bool done = false;

    while (!done && na < TOPK) {
        // ---- filtered histogram ----
        for (int i = tid; i < NBIN; i += TN) bins[i] = 0;
        if (tid == 0) { sint[1] = 0; sint[2] = 0; }
        __syncthreads();
#pragma unroll
        for (int t = 0; t < NSLOT; ++t) {
            float s = sc[t];
            if (s > 0.f) {
                u64 kk = pk(s, AIDX(t));
                if (kk < filter) atomicAdd(&bins[binOf(s)], 1);
            }
        }
        __syncthreads();

        // ---- select bin threshold B (wave0) ----
        if (tid < 64) {
            int lsum[18];
            int tot = 0;
#pragma unroll
            for (int k = 0; k < 18; ++k) { lsum[k] = bins[tid * 18 + k]; tot += lsum[k]; }
            int pfx = tot;
#pragma unroll
            for (int off = 1; off < 64; off <<= 1) {
                int o = __shfl_up(pfx, off, 64);
                if (lane >= off) pfx += o;
            }
            const int totalAll = __shfl(pfx, 63, 64);
            const int sufAbove = totalAll - pfx;
            const int tgt = totalAll < TARGET ? totalAll : TARGET;
            int run = 0, b1 = -1, b2 = 1 << 30;
#pragma unroll
            for (int k = 17; k >= 0; --k) {
                run += lsum[k];
                int suf = sufAbove + run;
                int b = tid * 18 + k;
                if (suf >= tgt && b > b1) b1 = b;
                if (suf <= CAPC && b < b2) b2 = b;
            }
#pragma unroll
            for (int off = 1; off < 64; off <<= 1) {
                int o1 = __shfl_xor(b1, off, 64); if (o1 > b1) b1 = o1;
                int o2 = __shfl_xor(b2, off, 64); if (o2 < b2) b2 = o2;
            }
            if (lane == 0) {
                sint[0] = b1 > b2 ? b1 : b2;
                sint[2] = (b2 == (1 << 30)) ? 1 : 0;
            }
        }
        __syncthreads();
        const int B = sint[0];
        const int degen = sint[2];

        if (!degen) {
            // ---- compact keys of bins >= B (ballot-aggregated; order fixed by sort) ----
#pragma unroll
            for (int t = 0; t < NSLOT; ++t) {
                float s = sc[t];
                bool pred = false; u64 kk = 0ull;
                if (s > 0.f && binOf(s) >= B) {
                    kk = pk(s, AIDX(t));
                    pred = (kk < filter);
                }
                u64 m = __ballot(pred);
                if (m) {
                    int bse = 0;
                    if (lane == 0) bse = atomicAdd(&sint[1], __popcll(m));
                    bse = __shfl(bse, 0, 64);
                    if (pred) {
                        int sl = bse + __popcll(m & ((1ull << lane) - 1ull));
                        skey[PHYS(sl)] = kk;
                    }
                }
            }
            __syncthreads();
            const int T = sint[1];
            if (T == 0) break;                       // exhausted
            for (int i = T + tid; i < CAPC; i += TN) skey[PHYS(i)] = 0ull;
            __syncthreads();

            // ---- hybrid bitonic sort 512 u64 desc: __shfl_xor for j<=32, LDS only j>=64
            // (identical network to LDS-only version; 6 LDS stages instead of 45) ----
            {
                u64 myk = skey[PHYS(tid)];
                for (int kk2 = 2; kk2 <= CAPC; kk2 <<= 1) {
                    for (int j = kk2 >> 1; j > 0; j >>= 1) {
                        u64 other;
                        if (j >= 64) {
                            skey[PHYS(tid)] = myk;
                            __syncthreads();
                            other = skey[PHYS(tid ^ j)];
                            __syncthreads();
                        } else {
                            other = __shfl_xor(myk, j, 64);
                        }
                        myk = bsel(myk, other, tid, kk2, j);
                    }
                }
                skey[PHYS(tid)] = myk;   // last cross-wave read was pre-barrier: safe
            }
            __syncthreads();

            // ---- prefetch candidate boxes in sorted order ----
            for (int p = tid; p < CAPC; p += TN) {
                u64 kk = skey[PHYS(p)];
                if (kk) sbox[p] = gb[upi(kk)];
            }
            __syncthreads();

            // ---- lazy walk (all waves redundantly; +1-deep register prefetch) ----
            u64 nk = skey[PHYS(0)];
            float4 nb = sbox[0];
            for (int p = 0; p < T; ++p) {
                u64 kk = nk; float4 cb = nb;
                if (p + 1 < T) { nk = skey[PHYS(p + 1)]; nb = sbox[p + 1]; }
                filter = kk;
                float ca = (cb.z - cb.x) * (cb.w - cb.y);
                bool kill = false;
                if (lane < na)      kill = killp(cb, ca, accA, arA);
                if (lane + 64 < na) kill = kill || killp(cb, ca, accB, arB);
                if (!__any(kill)) {
                    if (tid == 0) {
                        float* o = grows + na * 6;
                        o[0] = cb.x; o[1] = cb.y; o[2] = cb.z; o[3] = cb.w;
                        o[4] = upv(kk); o[5] = (float)(ci + 1);
                    }
                    if (na < 64) { if (lane == na) { accA = cb; arA = ca; } }
                    else if (lane == na - 64) { accB = cb; arB = ca; }
                    ++na;
                    if (na == TOPK) { done = true; break; }
                }
            }
            // next refill's LDS writes are gated by two barriers before any store,
            // so no race with waves still finishing this walk.
        } else {
            // ---- degenerate (one bin > CAPC; never on real data): single extractions ----
            while (na < TOPK) {
                u64 best = 0ull;
#pragma unroll
                for (int t = 0; t < NSLOT; ++t) {
                    float s = sc[t];
                    if (s > 0.f) {
                        u64 kk = pk(s, AIDX(t));
                        if (kk < filter && kk > best) best = kk;
                    }
                }
#pragma unroll
                for (int off = 1; off < 64; off <<= 1) best = umx(best, __shfl_xor(best, off, 64));
                if (lane == 0) red8[w] = best;
                __syncthreads();
                if (tid == 0) {
                    u64 bb = red8[0];
#pragma unroll
                    for (int q = 1; q < TN / 64; ++q) bb = umx(bb, red8[q]);
                    bkey = bb;
                    if (bb) bbox = gb[upi(bb)];
                }
                __syncthreads();
                u64 kk = bkey;
                if (!kk) break;
                filter = kk;
                float4 cb = bbox;
                float ca = (cb.z - cb.x) * (cb.w - cb.y);
                bool kill = false;
                if (lane < na)      kill = killp(cb, ca, accA, arA);
                if (lane + 64 < na) kill = kill || killp(cb, ca, accB, arB);
                if (!__any(kill)) {
                    if (tid == 0) {
                        float* o = grows + na * 6;
                        o[0] = cb.x; o[1] = cb.y; o[2] = cb.z; o[3] = cb.w;
                        o[4] = upv(kk); o[5] = (float)(ci + 1);
                    }
                    if (na < 64) { if (lane == na) { accA = cb; arA = ca; } }
                    else if (lane == na - 64) { accB = cb; arB = ca; }
                    ++na;
                }
                __syncthreads();
            }
            break;
        }
    }
    for (int j = na * 6 + tid; j < 600; j += TN) grows[j] = 0.f;
#undef AIDX
}

// Kernel 3: per image, bitonic sort of all 2048 padded candidate keys, gather top-100.
// key = (score_bits<<32) | (0xFFFFFFFF - flat_j), flat_j = (ci+1)*100 + pos. Exact
// lax.top_k order for positive scores; zero-score selections are all-zero rows in
// both ref (class-0 block / invalid rows) and ours -> value-identical output.
// R7: hybrid shuffle/LDS bitonic, 2 keys/thread. j==1 in-thread; 2<=j<=64 via
// __shfl_xor(j>>1); only j>=128 (10 stages) via LDS. Keys built directly in regs.
__global__ __launch_bounds__(1024) void topk_kernel(
    const float* __restrict__ rows, float* __restrict__ out) {
    __shared__ u64 skey[PHYS(2047) + 2];
    const int n = blockIdx.x, tid = threadIdx.x;
    const float* base = rows + (size_t)n * (NC * 600);
    const int i0 = tid << 1, i1 = i0 | 1;

    u64 k0 = 0ull, k1 = 0ull;
    if (i0 < 2000) {
        int ci = i0 / 100, pos = i0 - ci * 100;
        float s = base[ci * 600 + pos * 6 + 4];
        k0 = ((u64)__float_as_uint(s) << 32) | (u64)(0xFFFFFFFFu - (unsigned)(i0 + 100));
    }
    if (i1 < 2000) {
        int ci = i1 / 100, pos = i1 - ci * 100;
        float s = base[ci * 600 + pos * 6 + 4];
        k1 = ((u64)__float_as_uint(s) << 32) | (u64)(0xFFFFFFFFu - (unsigned)(i1 + 100));
    }

    for (int kk2 = 2; kk2 <= 2048; kk2 <<= 1) {
        for (int j = kk2 >> 1; j > 0; j >>= 1) {
            if (j >= 128) {
                skey[PHYS(i0)] = k0; skey[PHYS(i1)] = k1;
                __syncthreads();
                u64 o0 = skey[PHYS(i0 ^ j)], o1 = skey[PHYS(i1 ^ j)];
                __syncthreads();
                k0 = bsel(k0, o0, i0, kk2, j);
                k1 = bsel(k1, o1, i1, kk2, j);
            } else if (j >= 2) {
                u64 o0 = __shfl_xor(k0, j >> 1, 64);
                u64 o1 = __shfl_xor(k1, j >> 1, 64);
                k0 = bsel(k0, o0, i0, kk2, j);
                k1 = bsel(k1, o1, i1, kk2, j);
            } else {
                bool mx0 = ((i0 & kk2) == 0);   // (i1 & kk2) == (i0 & kk2) for kk2 >= 2
                u64 mx = umx(k0, k1), mn = umn(k0, k1);
                k0 = mx0 ? mx : mn; k1 = mx0 ? mn : mx;
            }
        }
    }
    skey[PHYS(i0)] = k0; skey[PHYS(i1)] = k1;   // last cross-wave read was pre-barrier
    __syncthreads();

    if (tid < 600) {
        int r = tid / 6, f = tid - (tid / 6) * 6;
        u64 kk = skey[PHYS(r)];
        float v = 0.f;
        if ((unsigned)(kk >> 32) != 0u) {
            int e = (int)(0xFFFFFFFFu - (unsigned)kk) - 100;
            int ci = e / 100, pos = e - ci * 100;
            v = base[ci * 600 + pos * 6 + f];
        }
        out[(size_t)n * 600 + tid] = v;
    }
}

extern "C" void kernel_launch(void* const* d_in, const int* in_sizes, int n_in,
                              void* d_out, int out_size, void* d_ws, size_t ws_size,
                              hipStream_t stream) {
    const float* cls = (const float*)d_in[0];   // [8,16384,21]
    const float* reg = (const float*)d_in[1];   // [8,16384,4]
    const float* anc = (const float*)d_in[2];   // [16384,4]
    float* out = (float*)d_out;                 // [8,100,6]

    // ws layout (floats): boxes 524288 | scores 2621440 | rows 96000
    float* boxes  = (float*)d_ws;
    float* scores = boxes + (size_t)N_IMG * A * 4;
    float* rows   = scores + (size_t)N_IMG * NC * A;

    preprocess_kernel<<<(N_IMG * A) / 256, 256, 0, stream>>>(cls, reg, anc, (float4*)boxes, scores);
    nms_kernel<<<N_IMG * NC, TN, 0, stream>>>((const float4*)boxes, scores, rows);
    topk_kernel<<<N_IMG, 1024, 0, stream>>>(rows, out);
}

// Round 2
// 142.555 us; speedup vs baseline: 1.0107x; 1.0097x over previous
//
#include <hip/hip_runtime.h>

// Detection post-process: softmax -> decode -> per-class LAZY NMS -> top-100.
// N=8 images, A=16384 anchors, C=21 classes (class 0 = background).
//
// R7 (143.9us): hybrid shuffle/LDS bitonic. Conflicts 250k->95k but nms 61.5->60.4:
// sort was ~1us of 61 -- NOT the pole. Bottom-up model says phases sum to ~26us vs
// 60 measured; the counters can't split phases inside one dispatch.
// R8: SPLIT nms into nms_select (load/hist/select/compact/sort -> ws) and nms_walk
// (chunk load + wave0-only walk). Wins: (a) walk loses the 2-waves/SIMD redundant
// issue contention (8 redundant walking waves -> 1), (b) candidate areas precomputed
// at gather, (c) next round's counters give the per-phase time split directly.
// Refill + degenerate paths keep the full loop inside nms_walk with wave0-
// authoritative verdicts broadcast via LDS (barrier convergence preserved).
// Exactness invariants (absmax 0.0 since R1):
//   - u64 key = (score_bits<<32)|~idx  => exact (score desc, idx asc) total order
//   - monotone bin(float bits) => bin-threshold selection is a key-order cut
//   - chunk = ALL keys in bins >= B => after walking chunk, filter = min chunk key
//     and remaining candidates are exactly keys < filter (refill identical to R7)
//   - lazy NMS: dead entries never kill => test pops against accepted set only
//   - division-free EXACT IoU predicate:
//     RN_f32(inter/un) > 0.45f  <=>  (double)inter > ((double)0.45f + 2^-26)*(double)un

typedef unsigned long long u64;

#define N_IMG 8
#define A     16384
#define NCLS  21
#define NC    20
#define TOPK  100
#define PROB_THR 0.05f

#define TN     512         // nms threads (8 waves)
#define NSLOT  32          // scores per thread
#define NBIN   1152        // score-bit bins: (bits>>15)-31385 spans (0.05,1]
#define BINOFF 31385
#define CAPC   512         // chunk capacity (sorted); expected pops ~150-250
#define TARGET 384

#define PHYS(i) ((i) + ((i) >> 4))   // LDS u64 swizzle: breaks power-of-2 strides

#define MIDTHR ((double)0.45f + 0x1p-26)

#define AIDX(t_) ((tid << 2) + (((t_) >> 2) << 11) + ((t_) & 3))

__device__ __forceinline__ u64 pk(float v, int i) {
    return (v > 0.f) ? (((u64)__float_as_uint(v) << 32) | (u64)(unsigned)(~(unsigned)i)) : 0ull;
}
__device__ __forceinline__ float upv(u64 k) { return __uint_as_float((unsigned)(k >> 32)); }
__device__ __forceinline__ int   upi(u64 k) { return (int)(~(unsigned)k); }
__device__ __forceinline__ u64 umx(u64 a, u64 b) { return a > b ? a : b; }
__device__ __forceinline__ u64 umn(u64 a, u64 b) { return a < b ? a : b; }

// bitonic compare-exchange keep-rule for element i at stage (k,j):
// region (i&k)==0 sorts descending; lower partner ((i&j)==0) keeps max there.
__device__ __forceinline__ u64 bsel(u64 mine, u64 other, int i, int k, int j) {
    bool keep_max = ((i & k) == 0) == ((i & j) == 0);
    return keep_max ? umx(mine, other) : umn(mine, other);
}

__device__ __forceinline__ int binOf(float s) {
    int b = (int)(__float_as_uint(s) >> 15) - BINOFF;
    return b < 0 ? 0 : (b > NBIN - 1 ? NBIN - 1 : b);
}

// exact ref predicate: RN(inter/union) > 0.45f
__device__ __forceinline__ bool killp(float4 b, float ab, float4 s, float as_) {
    float lx = fmaxf(s.x, b.x), ly = fmaxf(s.y, b.y);
    float rx = fminf(s.z, b.z), ry = fminf(s.w, b.w);
    float iw = fmaxf(rx - lx, 0.f), ih = fmaxf(ry - ly, 0.f);
    float inter = iw * ih;
    float un = as_ + ab - inter;
    return (double)inter > MIDTHR * (double)un;
}

// wave0 selects the bin threshold B into sint[0]; degenerate flag into sint[2].
__device__ __forceinline__ void select_bin(int* bins, int* sint, int tid, int lane) {
    if (tid < 64) {
        int lsum[18];
        int tot = 0;
#pragma unroll
        for (int k = 0; k < 18; ++k) { lsum[k] = bins[tid * 18 + k]; tot += lsum[k]; }
        int pfx = tot;
#pragma unroll
        for (int off = 1; off < 64; off <<= 1) {
            int o = __shfl_up(pfx, off, 64);
            if (lane >= off) pfx += o;
        }
        const int totalAll = __shfl(pfx, 63, 64);
        const int sufAbove = totalAll - pfx;
        const int tgt = totalAll < TARGET ? totalAll : TARGET;
        int run = 0, b1 = -1, b2 = 1 << 30;
#pragma unroll
        for (int k = 17; k >= 0; --k) {
            run += lsum[k];
            int suf = sufAbove + run;
            int b = tid * 18 + k;
            if (suf >= tgt && b > b1) b1 = b;
            if (suf <= CAPC && b < b2) b2 = b;
        }
#pragma unroll
        for (int off = 1; off < 64; off <<= 1) {
            int o1 = __shfl_xor(b1, off, 64); if (o1 > b1) b1 = o1;
            int o2 = __shfl_xor(b2, off, 64); if (o2 < b2) b2 = o2;
        }
        if (lane == 0) {
            sint[0] = b1 > b2 ? b1 : b2;
            sint[2] = (b2 == (1 << 30)) ? 1 : 0;
        }
    }
}

// hybrid bitonic sort-512 desc over skey (swizzled); returns sorted[tid] in register.
// __shfl_xor for j<=32 (no barrier), LDS only for j>=64 (6 stages).
__device__ __forceinline__ u64 sort512(u64* skey, int tid) {
    u64 myk = skey[PHYS(tid)];
    for (int kk2 = 2; kk2 <= CAPC; kk2 <<= 1) {
        for (int j = kk2 >> 1; j > 0; j >>= 1) {
            u64 other;
            if (j >= 64) {
                skey[PHYS(tid)] = myk;
                __syncthreads();
                other = skey[PHYS(tid ^ j)];
                __syncthreads();
            } else {
                other = __shfl_xor(myk, j, 64);
            }
            myk = bsel(myk, other, tid, kk2, j);
        }
    }
    return myk;
}

// Kernel 1: softmax + threshold -> scores[N][NC][A]; SSD decode -> clamped corner boxes.
__global__ __launch_bounds__(256) void preprocess_kernel(
    const float* __restrict__ cls, const float* __restrict__ reg,
    const float* __restrict__ anc, float4* __restrict__ boxes,
    float* __restrict__ scores) {
    __shared__ __align__(16) float lcls[256 * NCLS];
    const int tid = threadIdx.x;
    const int t = blockIdx.x * 256 + tid;

    const float4* src = (const float4*)(cls + (size_t)blockIdx.x * (256 * NCLS));
    float4* dst = (float4*)lcls;
    for (int i = tid; i < (256 * NCLS) / 4; i += 256) dst[i] = src[i];
    __syncthreads();

    const int n = t >> 14;
    const int a = t & (A - 1);
    const float* c = lcls + tid * NCLS;
    float z[NCLS];
    float m = -1e30f;
#pragma unroll
    for (int k = 0; k < NCLS; ++k) { z[k] = c[k]; m = fmaxf(m, z[k]); }
    float s = 0.f;
#pragma unroll
    for (int k = 0; k < NCLS; ++k) { z[k] = expf(z[k] - m); s += z[k]; }
    const float inv = 1.f / s;
#pragma unroll
    for (int k = 0; k < NC; ++k) {
        float p = z[k + 1] * inv;
        scores[(((size_t)n * NC + k) << 14) + a] = (p > PROB_THR) ? p : -1.f;
    }

    const float4 l4 = ((const float4*)reg)[t];
    const float4 an = ((const float4*)anc)[a];
    const float cx = an.x + l4.x * 0.1f * an.z;
    const float cy = an.y + l4.y * 0.1f * an.w;
    const float w  = an.z * expf(l4.z * 0.2f);
    const float h  = an.w * expf(l4.w * 0.2f);
    float x0 = fminf(fmaxf(cx - 0.5f * w, 0.f), 1.f);
    float y0 = fminf(fmaxf(cy - 0.5f * h, 0.f), 1.f);
    float x1 = fminf(fmaxf(cx + 0.5f * w, 0.f), 1.f);
    float y1 = fminf(fmaxf(cy + 0.5f * h, 0.f), 1.f);
    boxes[t] = make_float4(x0, y0, x1, y1);
}

// Kernel 2a: per (n,ci): load scores -> histogram -> select B -> compact -> sort-512
// -> sorted keys to ws. meta[blk]: T (>0), 0 (no candidates), -1 (degenerate bin).
__global__ __launch_bounds__(TN) void nms_select_kernel(
    const float* __restrict__ scores, u64* __restrict__ keyg, int* __restrict__ meta) {
    __shared__ int bins[NBIN];
    __shared__ u64 skey[PHYS(CAPC - 1) + 2];
    __shared__ int sint[3];

    const int blk = blockIdx.x;
    const int tid = threadIdx.x, lane = tid & 63;
    const float* gs = scores + ((size_t)blk << 14);
    u64* gk = keyg + (size_t)blk * CAPC;

    float sc[NSLOT];
    const float4* gs4 = (const float4*)gs;
#pragma unroll
    for (int k = 0; k < NSLOT / 4; ++k) {
        float4 v = gs4[tid + (k << 9)];
        sc[k * 4 + 0] = v.x; sc[k * 4 + 1] = v.y; sc[k * 4 + 2] = v.z; sc[k * 4 + 3] = v.w;
    }

    for (int i = tid; i < NBIN; i += TN) bins[i] = 0;
    if (tid == 0) { sint[1] = 0; sint[2] = 0; }
    __syncthreads();
#pragma unroll
    for (int t = 0; t < NSLOT; ++t) {
        float s = sc[t];
        if (s > 0.f) atomicAdd(&bins[binOf(s)], 1);   // filter=~0: every key qualifies
    }
    __syncthreads();

    select_bin(bins, sint, tid, lane);
    __syncthreads();
    const int B = sint[0];
    if (sint[2]) { if (tid == 0) meta[blk] = -1; return; }   // degenerate

    // compact keys of bins >= B (ballot-aggregated; order fixed by sort)
#pragma unroll
    for (int t = 0; t < NSLOT; ++t) {
        float s = sc[t];
        bool pred = false; u64 kk = 0ull;
        if (s > 0.f && binOf(s) >= B) { kk = pk(s, AIDX(t)); pred = true; }
        u64 m = __ballot(pred);
        if (m) {
            int bse = 0;
            if (lane == 0) bse = atomicAdd(&sint[1], __popcll(m));
            bse = __shfl(bse, 0, 64);
            if (pred) {
                int sl = bse + __popcll(m & ((1ull << lane) - 1ull));
                skey[PHYS(sl)] = kk;
            }
        }
    }
    __syncthreads();
    const int T = sint[1];
    if (T == 0) { if (tid == 0) meta[blk] = 0; return; }
    for (int i = T + tid; i < CAPC; i += TN) skey[PHYS(i)] = 0ull;
    __syncthreads();

    u64 myk = sort512(skey, tid);
    gk[tid] = myk;                       // coalesced store of sorted chunk
    if (tid == 0) meta[blk] = T;
}

// Kernel 2b: per (n,ci): load sorted chunk -> gather boxes(+areas) -> wave0 lazy walk.
// Refill (rare: chunk exhausted before 100 accepts) and degenerate paths run the
// full pipeline in-kernel; wave0 verdicts broadcast so barriers stay convergent.
__global__ __launch_bounds__(TN) void nms_walk_kernel(
    const float4* __restrict__ boxes, const float* __restrict__ scores,
    const u64* __restrict__ keyg, const int* __restrict__ meta,
    float* __restrict__ rows) {
    __shared__ int bins[NBIN];
    __shared__ u64 skey[PHYS(CAPC - 1) + 2];
    __shared__ __align__(16) float4 sbox[CAPC];
    __shared__ float sarea[CAPC];
    __shared__ u64 red8[TN / 64];
    __shared__ u64 bkey;
    __shared__ __align__(16) float4 bbox;
    __shared__ int sint[3];
    __shared__ u64 bfil;
    __shared__ int bna, bdone, bacc;

    const int blk = blockIdx.x, n = blk / NC, ci = blk % NC;
    const int tid = threadIdx.x, lane = tid & 63, w = tid >> 6;
    const float* gs = scores + ((size_t)blk << 14);
    const float4* gb = boxes + ((size_t)n << 14);
    const u64* gk = keyg + (size_t)blk * CAPC;
    float* grows = rows + (size_t)blk * 600;

    const int T0 = meta[blk];
    if (T0 == 0) {
        for (int j = tid; j < 600; j += TN) grows[j] = 0.f;
        return;
    }

    float4 accA, accB;
    float arA = 0.f, arB = 0.f;
    int na = 0;
    u64 filter = ~0ull;
    bool done = false;
    float sc[NSLOT];
    bool loaded = false;
    int chunkT = -1;

    if (T0 > 0) {
        // first chunk comes presorted from nms_select
        for (int i = tid; i < CAPC; i += TN) skey[PHYS(i)] = gk[i];
        __syncthreads();
        for (int p = tid; p < CAPC; p += TN) {
            u64 kk = skey[PHYS(p)];
            if (kk) {
                float4 b = gb[upi(kk)];
                sbox[p] = b;
                sarea[p] = (b.z - b.x) * (b.w - b.y);
            }
        }
        __syncthreads();
        chunkT = T0;
    }

    while (!done && na < TOPK) {
        if (chunkT < 0) {
            // ---- refill: full hist/select/compact/sort (all waves) ----
            if (!loaded) {
                const float4* gs4 = (const float4*)gs;
#pragma unroll
                for (int k = 0; k < NSLOT / 4; ++k) {
                    float4 v = gs4[tid + (k << 9)];
                    sc[k * 4 + 0] = v.x; sc[k * 4 + 1] = v.y;
                    sc[k * 4 + 2] = v.z; sc[k * 4 + 3] = v.w;
                }
                loaded = true;
            }
            for (int i = tid; i < NBIN; i += TN) bins[i] = 0;
            if (tid == 0) { sint[1] = 0; sint[2] = 0; }
            __syncthreads();
#pragma unroll
            for (int t = 0; t < NSLOT; ++t) {
                float s = sc[t];
                if (s > 0.f) {
                    u64 kk = pk(s, AIDX(t));
                    if (kk < filter) atomicAdd(&bins[binOf(s)], 1);
                }
            }
            __syncthreads();
            select_bin(bins, sint, tid, lane);
            __syncthreads();
            const int B = sint[0];
            if (!sint[2]) {
#pragma unroll
                for (int t = 0; t < NSLOT; ++t) {
                    float s = sc[t];
                    bool pred = false; u64 kk = 0ull;
                    if (s > 0.f && binOf(s) >= B) {
                        kk = pk(s, AIDX(t));
                        pred = (kk < filter);
                    }
                    u64 m = __ballot(pred);
                    if (m) {
                        int bse = 0;
                        if (lane == 0) bse = atomicAdd(&sint[1], __popcll(m));
                        bse = __shfl(bse, 0, 64);
                        if (pred) {
                            int sl = bse + __popcll(m & ((1ull << lane) - 1ull));
                            skey[PHYS(sl)] = kk;
                        }
                    }
                }
                __syncthreads();
                const int T = sint[1];
                if (T == 0) break;                   // exhausted
                for (int i = T + tid; i < CAPC; i += TN) skey[PHYS(i)] = 0ull;
                __syncthreads();
                u64 myk = sort512(skey, tid);
                skey[PHYS(tid)] = myk;
                __syncthreads();
                for (int p = tid; p < CAPC; p += TN) {
                    u64 kk = skey[PHYS(p)];
                    if (kk) {
                        float4 b = gb[upi(kk)];
                        sbox[p] = b;
                        sarea[p] = (b.z - b.x) * (b.w - b.y);
                    }
                }
                __syncthreads();
                chunkT = T;
            } else {
                // ---- degenerate (one bin > CAPC; never on real data): single
                // extractions, wave0-authoritative verdict broadcast ----
                while (na < TOPK) {
                    u64 best = 0ull;
#pragma unroll
                    for (int t = 0; t < NSLOT; ++t) {
                        float s = sc[t];
                        if (s > 0.f) {
                            u64 kk = pk(s, AIDX(t));
                            if (kk < filter && kk > best) best = kk;
                        }
                    }
#pragma unroll
                    for (int off = 1; off < 64; off <<= 1) best = umx(best, __shfl_xor(best, off, 64));
                    if (lane == 0) red8[w] = best;
                    __syncthreads();
                    if (tid == 0) {
                        u64 bb = red8[0];
#pragma unroll
                        for (int q = 1; q < TN / 64; ++q) bb = umx(bb, red8[q]);
                        bkey = bb;
                        if (bb) bbox = gb[upi(bb)];
                    }
                    __syncthreads();
                    u64 kk = bkey;
                    if (!kk) break;
                    filter = kk;
                    if (w == 0) {
                        float4 cb = bbox;
                        float ca = (cb.z - cb.x) * (cb.w - cb.y);
                        bool kill = false;
                        if (lane < na)      kill = killp(cb, ca, accA, arA);
                        if (lane + 64 < na) kill = kill || killp(cb, ca, accB, arB);
                        int acc = __any(kill) ? 0 : 1;
                        if (lane == 0) bacc = acc;
                        if (acc) {
                            if (lane == 0) {
                                float* o = grows + na * 6;
                                o[0] = cb.x; o[1] = cb.y; o[2] = cb.z; o[3] = cb.w;
                                o[4] = upv(kk); o[5] = (float)(ci + 1);
                            }
                            if (na < 64) { if (lane == na) { accA = cb; arA = ca; } }
                            else if (lane == na - 64) { accB = cb; arB = ca; }
                        }
                    }
                    __syncthreads();
                    if (bacc) ++na;                  // uniform across block
                    __syncthreads();
                }
                break;
            }
        }

        // ---- lazy walk: wave0 only; others park at the barrier ----
        if (w == 0) {
            u64 nk = skey[PHYS(0)];
            float4 nb = sbox[0];
            float nar = sarea[0];
            for (int p = 0; p < chunkT; ++p) {
                u64 kk = nk; float4 cb = nb; float ca = nar;
                if (p + 1 < chunkT) { nk = skey[PHYS(p + 1)]; nb = sbox[p + 1]; nar = sarea[p + 1]; }
                filter = kk;
                bool kill = false;
                if (lane < na)      kill = killp(cb, ca, accA, arA);
                if (lane + 64 < na) kill = kill || killp(cb, ca, accB, arB);
                if (!__any(kill)) {
                    if (lane == 0) {
                        float* o = grows + na * 6;
                        o[0] = cb.x; o[1] = cb.y; o[2] = cb.z; o[3] = cb.w;
                        o[4] = upv(kk); o[5] = (float)(ci + 1);
                    }
                    if (na < 64) { if (lane == na) { accA = cb; arA = ca; } }
                    else if (lane == na - 64) { accB = cb; arB = ca; }
                    ++na;
                    if (na == TOPK) { done = true; break; }
                }
            }
            if (lane == 0) { bfil = filter; bna = na; bdone = done ? 1 : 0; }
        }
        __syncthreads();
        filter = bfil; na = bna; done = (bdone != 0);
        chunkT = -1;
        // next refill's first LDS writes (bins) are unused here; skey/sbox rewritten
        // only after further barriers -> no race with this broadcast.
    }
    for (int j = na * 6 + tid; j < 600; j += TN) grows[j] = 0.f;
}

// Kernel 3: per image, bitonic sort of all 2048 padded candidate keys, gather top-100.
// key = (score_bits<<32) | (0xFFFFFFFF - flat_j), flat_j = (ci+1)*100 + pos. Exact
// lax.top_k order for positive scores; zero-score selections are all-zero rows in
// both ref (class-0 block / invalid rows) and ours -> value-identical output.
// Hybrid shuffle/LDS bitonic, 2 keys/thread; only j>=128 via LDS.
__global__ __launch_bounds__(1024) void topk_kernel(
    const float* __restrict__ rows, float* __restrict__ out) {
    __shared__ u64 skey[PHYS(2047) + 2];
    const int n = blockIdx.x, tid = threadIdx.x;
    const float* base = rows + (size_t)n * (NC * 600);
    const int i0 = tid << 1, i1 = i0 | 1;

    u64 k0 = 0ull, k1 = 0ull;
    if (i0 < 2000) {
        int ci = i0 / 100, pos = i0 - ci * 100;
        float s = base[ci * 600 + pos * 6 + 4];
        k0 = ((u64)__float_as_uint(s) << 32) | (u64)(0xFFFFFFFFu - (unsigned)(i0 + 100));
    }
    if (i1 < 2000) {
        int ci = i1 / 100, pos = i1 - ci * 100;
        float s = base[ci * 600 + pos * 6 + 4];
        k1 = ((u64)__float_as_uint(s) << 32) | (u64)(0xFFFFFFFFu - (unsigned)(i1 + 100));
    }

    for (int kk2 = 2; kk2 <= 2048; kk2 <<= 1) {
        for (int j = kk2 >> 1; j > 0; j >>= 1) {
            if (j >= 128) {
                skey[PHYS(i0)] = k0; skey[PHYS(i1)] = k1;
                __syncthreads();
                u64 o0 = skey[PHYS(i0 ^ j)], o1 = skey[PHYS(i1 ^ j)];
                __syncthreads();
                k0 = bsel(k0, o0, i0, kk2, j);
                k1 = bsel(k1, o1, i1, kk2, j);
            } else if (j >= 2) {
                u64 o0 = __shfl_xor(k0, j >> 1, 64);
                u64 o1 = __shfl_xor(k1, j >> 1, 64);
                k0 = bsel(k0, o0, i0, kk2, j);
                k1 = bsel(k1, o1, i1, kk2, j);
            } else {
                bool mx0 = ((i0 & kk2) == 0);   // (i1 & kk2) == (i0 & kk2) for kk2 >= 2
                u64 mx = umx(k0, k1), mn = umn(k0, k1);
                k0 = mx0 ? mx : mn; k1 = mx0 ? mn : mx;
            }
        }
    }
    skey[PHYS(i0)] = k0; skey[PHYS(i1)] = k1;   // last cross-wave read was pre-barrier
    __syncthreads();

    if (tid < 600) {
        int r = tid / 6, f = tid - (tid / 6) * 6;
        u64 kk = skey[PHYS(r)];
        float v = 0.f;
        if ((unsigned)(kk >> 32) != 0u) {
            int e = (int)(0xFFFFFFFFu - (unsigned)kk) - 100;
            int ci = e / 100, pos = e - ci * 100;
            v = base[ci * 600 + pos * 6 + f];
        }
        out[(size_t)n * 600 + tid] = v;
    }
}

extern "C" void kernel_launch(void* const* d_in, const int* in_sizes, int n_in,
                              void* d_out, int out_size, void* d_ws, size_t ws_size,
                              hipStream_t stream) {
    const float* cls = (const float*)d_in[0];   // [8,16384,21]
    const float* reg = (const float*)d_in[1];   // [8,16384,4]
    const float* anc = (const float*)d_in[2];   // [16384,4]
    float* out = (float*)d_out;                 // [8,100,6]

    // ws layout (floats): boxes 524288 | scores 2621440 | rows 96000 |
    //                     keyg 160*512 u64 (=163840 floats, 8B aligned) | meta 160 ints
    float* boxes  = (float*)d_ws;
    float* scores = boxes + (size_t)N_IMG * A * 4;
    float* rows   = scores + (size_t)N_IMG * NC * A;
    u64*   keyg   = (u64*)(rows + (size_t)N_IMG * NC * 600);
    int*   meta   = (int*)(keyg + (size_t)N_IMG * NC * CAPC);

    preprocess_kernel<<<(N_IMG * A) / 256, 256, 0, stream>>>(cls, reg, anc, (float4*)boxes, scores);
    nms_select_kernel<<<N_IMG * NC, TN, 0, stream>>>(scores, keyg, meta);
    nms_walk_kernel<<<N_IMG * NC, TN, 0, stream>>>((const float4*)boxes, scores, keyg, meta, rows);
    topk_kernel<<<N_IMG, 1024, 0, stream>>>(rows, out);
}